// Round 7
// baseline (210.759 us; speedup 1.0000x reference)
//
#include <hip/hip_runtime.h>
#include <hip/hip_bf16.h>
#include <cstdint>
#include <cstddef>

// Problem constants
#define CIN_K  512
#define WW_    38
#define BHW    1444          // 38*38
#define NOUT   255
#define MTOT   46208         // 32*1444 == 722*64

#define BM     64            // m-rows per block
#define EP_DW  260           // fp32 dwords per epilogue row (32 rows x 260 dw = 33,280 B)

typedef __attribute__((ext_vector_type(8))) short  bf16x8;
typedef __attribute__((ext_vector_type(4))) float  floatx4;

static __device__ __forceinline__ unsigned f2bf(float f) {
    unsigned u = __builtin_bit_cast(unsigned, f);
    return (u + 0x7FFFu + ((u >> 16) & 1u)) >> 16;   // RNE to bf16
}

// RNE pack of 2 floats -> 1 dword of 2 bf16 (compiler emits v_cvt_pk_bf16_f32)
static __device__ __forceinline__ unsigned pk2bf(float a, float b) {
    __hip_bfloat162 h = __float22bfloat162_rn(make_float2(a, b));
    unsigned r;
    __builtin_memcpy(&r, &h, 4);
    return r;
}

// ---- pass 1: cw fp32 [255][512] -> wb bf16 [256][512], row 255 zeroed ----
__global__ void conv_w_to_bf16(const float* __restrict__ cw,
                               unsigned short* __restrict__ wb) {
    int tg   = blockIdx.x * 256 + threadIdx.x;   // 0..16383
    int base = tg * 8;
    int n    = base >> 9;
    unsigned rr[4] = {0u, 0u, 0u, 0u};
    if (n < NOUT) {
        float4 v0 = *(const float4*)(cw + base);
        float4 v1 = *(const float4*)(cw + base + 4);
        rr[0] = f2bf(v0.x) | (f2bf(v0.y) << 16);
        rr[1] = f2bf(v0.z) | (f2bf(v0.w) << 16);
        rr[2] = f2bf(v1.x) | (f2bf(v1.y) << 16);
        rr[3] = f2bf(v1.z) | (f2bf(v1.w) << 16);
    }
    *(uint4*)(wb + base) = *(uint4*)rr;
}

// ---- pass 2: barrier-free dataflow GEMM + fused YOLO decode ----
// Block: 64 m x 256 n, grid = 722 (XCD-swizzled). NO A-staging, NO LDS, NO
// barriers in the K-loop: each lane loads its MFMA A-fragment directly from
// xin (lane l15 = m-row -> 16-lane 64-B coalesced segments; i=0..3 adjacent
// -> full 128-B lines; 4 waves re-hit the slab via L1/L2). Compiler is free
// to pipeline loads across K-steps -> deep MLP (the thing every staged
// variant lacked, rounds 0-6 all 71-90 us at <1.7 TB/s).
// LDS only for the proven store-transpose epilogue (R6: direct stores
// amplified WRITE 46->81 MB).
__global__ __launch_bounds__(256, 3)
void yolo_head(const float* __restrict__ xin,          // [32,512,38,38] fp32
               const unsigned short* __restrict__ wb,  // [256,512] bf16
               const float* __restrict__ cb,           // [255] fp32
               float* __restrict__ out)                // [46208,255] fp32
{
    __shared__ unsigned smem[32 * EP_DW];              // 33,280 B (epilogue only)

    const int t    = threadIdx.x;
    const int w    = t >> 6;       // wave id -> n-slice w*64
    const int lane = t & 63;
    const int l15  = lane & 15;
    const int q    = lane >> 4;

    // bijective chunked XCD swizzle: nwg = 722 = 8*90 + 2.
    const int orig = blockIdx.x;
    const int xcd  = orig & 7;
    const int rank = orig >> 3;
    const int wgid = (xcd < 2 ? xcd * 91 : 182 + (xcd - 2) * 90) + rank;
    const int m0   = wgid * BM;

    // Per-i A base pointers: m = m0 + i*16 + l15 (per-lane batch index),
    // q*8 k-offset folded in. Load for (kc,u) is pa[i] + (kc*32+u)*BHW.
    const float* pa[4];
#pragma unroll
    for (int i = 0; i < 4; ++i) {
        int m  = m0 + i * 16 + l15;
        int bi = m / BHW;
        int hw = m - bi * BHW;
        pa[i] = xin + (size_t)bi * (CIN_K * BHW) + hw + (size_t)(q * 8) * BHW;
    }

    floatx4 acc[4][4];
#pragma unroll
    for (int i = 0; i < 4; ++i)
#pragma unroll
        for (int j = 0; j < 4; ++j)
            acc[i][j] = (floatx4){0.f, 0.f, 0.f, 0.f};

    // B frag addr: n = w*64 + j*16 + l15, k = kc*32 + q*8
    const unsigned short* pbw = wb + (size_t)(w * 64 + l15) * CIN_K + q * 8;

    // -------- hot loop: 16 K-steps, ZERO barriers, pure dataflow -----------
#pragma unroll
    for (int kc = 0; kc < 16; ++kc) {
        bf16x8 bfr[4], af[4];
#pragma unroll
        for (int j = 0; j < 4; ++j) {
            uint4 bv = *(const uint4*)(pbw + (size_t)j * 16 * CIN_K + kc * 32);
            bfr[j] = __builtin_bit_cast(bf16x8, bv);
        }
#pragma unroll
        for (int i = 0; i < 4; ++i) {
            float a8[8];
#pragma unroll
            for (int u = 0; u < 8; ++u)
                a8[u] = pa[i][(size_t)(kc * 32 + u) * BHW];
            unsigned d[4];
#pragma unroll
            for (int e = 0; e < 4; ++e)
                d[e] = pk2bf(a8[2 * e], a8[2 * e + 1]);
            af[i] = __builtin_bit_cast(bf16x8, *(uint4*)d);
        }
#pragma unroll
        for (int i = 0; i < 4; ++i)
#pragma unroll
            for (int j = 0; j < 4; ++j)
                acc[i][j] = __builtin_amdgcn_mfma_f32_16x16x32_bf16(
                                af[i], bfr[j], acc[i][j], 0, 0, 0);
    }

    // -------- fused YOLO decode (in place on acc) --------------------------
    // C/D layout: col(n) = l15 (+16j), row(m) = i*16 + q*4 + r
#pragma unroll
    for (int j = 0; j < 4; ++j) {
        int   n    = w * 64 + j * 16 + l15;
        int   nc   = n < NOUT ? n : NOUT - 1;
        int   ai   = nc / 85;
        int   ji   = nc - ai * 85;
        float bias = cb[nc];
        float aw   = (ai == 0) ? 30.f : (ai == 1) ? 62.f : 59.f;
        float ah   = (ai == 0) ? 61.f : (ai == 1) ? 45.f : 119.f;
#pragma unroll
        for (int i = 0; i < 4; ++i)
#pragma unroll
            for (int r = 0; r < 4; ++r) {
                int   md  = m0 + i * 16 + q * 4 + r;
                int   rem = md % BHW;
                int   hh  = rem / WW_;
                float v   = acc[i][j][r] + bias;
                float res;
                if (ji == 0)      res = (1.f / (1.f + __expf(-v)) + (float)(rem - hh * WW_)) * 16.f;
                else if (ji == 1) res = (1.f / (1.f + __expf(-v)) + (float)hh) * 16.f;
                else if (ji == 2) res = __expf(v) * aw;
                else if (ji == 3) res = __expf(v) * ah;
                else              res = v;
                acc[i][j][r] = res;
            }
    }

    // -------- epilogue: LDS transpose + aligned stores, 2 passes of 32 rows -
    float* EP = (float*)smem;
#pragma unroll
    for (int p = 0; p < 2; ++p) {
        __syncthreads();                   // previous LDS readers done
#pragma unroll
        for (int i2 = 0; i2 < 2; ++i2) {
            const int i = p * 2 + i2;
#pragma unroll
            for (int j = 0; j < 4; ++j)
#pragma unroll
                for (int r = 0; r < 4; ++r)
                    EP[(i2 * 16 + q * 4 + r) * EP_DW + w * 64 + j * 16 + l15] =
                        acc[i][j][r];
        }
        __syncthreads();

        // wave w stores rows [p*32 + w*8, +8): 8*255 = 2040 floats, 16B-aligned
        const float* EPb = (const float*)smem + (w * 8) * EP_DW;
        float*       ob  = out + (size_t)(m0 + p * 32 + w * 8) * NOUT;
#pragma unroll
        for (int s2 = 0; s2 < 8; ++s2) {
            int f4 = s2 * 64 + lane;       // float4 index, 0..509
            if (f4 < 510) {
                int   f = f4 * 4;
                float vs[4];
#pragma unroll
                for (int e = 0; e < 4; ++e) {
                    int fe = f + e;
                    int mr = fe / NOUT;
                    int x  = fe - mr * NOUT;
                    vs[e]  = EPb[mr * EP_DW + x];
                }
                *(float4*)(ob + f) = make_float4(vs[0], vs[1], vs[2], vs[3]);
            }
        }
    }
}

extern "C" void kernel_launch(void* const* d_in, const int* in_sizes, int n_in,
                              void* d_out, int out_size, void* d_ws, size_t ws_size,
                              hipStream_t stream) {
    const float* xin = (const float*)d_in[0];
    const float* cw  = (const float*)d_in[1];
    const float* cb  = (const float*)d_in[2];
    float*       out = (float*)d_out;
    unsigned short* wb = (unsigned short*)d_ws;   // 256*512*2 = 256 KiB

    hipLaunchKernelGGL(conv_w_to_bf16, dim3(64), dim3(256), 0, stream, cw, wb);
    hipLaunchKernelGGL(yolo_head, dim3(MTOT / BM), dim3(256), 0, stream,
                       xin, wb, cb, out);
}

// Round 8
// 182.187 us; speedup vs baseline: 1.1568x; 1.1568x over previous
//
#include <hip/hip_runtime.h>
#include <hip/hip_bf16.h>
#include <cstdint>
#include <cstddef>

// Problem constants
#define CIN_K  512
#define WW_    38
#define BHW    1444          // 38*38
#define NOUT   255
#define MTOT   46208         // 32*1444 == 722*64

#define BM     64            // m-rows per block
#define KCH    128           // k per chunk; 4 chunks cover K=512
#define ROWE   132           // bf16 elems per As row (128 + 4 pad), 66 dw
#define CH_DW  (64 * 66)     // dwords per chunk buffer = 16,896 B
#define EP_DW  260           // fp32 dwords per epilogue row (32 x 260 = 33,280 B)

typedef __attribute__((ext_vector_type(8))) short  bf16x8;
typedef __attribute__((ext_vector_type(4))) float  floatx4;

static __device__ __forceinline__ unsigned f2bf(float f) {
    unsigned u = __builtin_bit_cast(unsigned, f);
    return (u + 0x7FFFu + ((u >> 16) & 1u)) >> 16;   // RNE to bf16
}

// RNE pack of 2 floats -> 1 dword of 2 bf16 (compiler emits v_cvt_pk_bf16_f32)
static __device__ __forceinline__ unsigned pk2bf(float a, float b) {
    __hip_bfloat162 h = __float22bfloat162_rn(make_float2(a, b));
    unsigned r;
    __builtin_memcpy(&r, &h, 4);
    return r;
}

// ---- pass 1: cw fp32 [255][512] -> wb bf16 [256][512], row 255 zeroed ----
__global__ void conv_w_to_bf16(const float* __restrict__ cw,
                               unsigned short* __restrict__ wb) {
    int tg   = blockIdx.x * 256 + threadIdx.x;   // 0..16383
    int base = tg * 8;
    int n    = base >> 9;
    unsigned rr[4] = {0u, 0u, 0u, 0u};
    if (n < NOUT) {
        float4 v0 = *(const float4*)(cw + base);
        float4 v1 = *(const float4*)(cw + base + 4);
        rr[0] = f2bf(v0.x) | (f2bf(v0.y) << 16);
        rr[1] = f2bf(v0.z) | (f2bf(v0.w) << 16);
        rr[2] = f2bf(v1.x) | (f2bf(v1.y) << 16);
        rr[3] = f2bf(v1.z) | (f2bf(v1.w) << 16);
    }
    *(uint4*)(wb + base) = *(uint4*)rr;
}

// ---- pass 2: double-buffered chunk-pipelined GEMM + fused YOLO decode ----
// Block: 64 m x 256 n, grid = 722 (XCD-swizzled). 4 K-chunks of 128,
// 2 LDS buffers. Prefetch for chunk c+2 is issued AFTER the barrier that
// publishes chunk c+1 -> those loads stay in flight across the whole
// COMPUTE(c+1) phase and are drained exactly at the barrier where they're
// needed (rounds 0-7 lesson: __syncthreads drains vmcnt(0), so loads issued
// BEFORE a barrier expose their full latency serially -> 1.66 TB/s cap).
// launch_bounds(256,3): 170-VGPR budget keeps the 32-float prefetch live
// (R3's sink was a 64-VGPR squeeze); 3 blocks/CU matches grid supply 2.82.
__global__ __launch_bounds__(256, 3)
void yolo_head(const float* __restrict__ xin,          // [32,512,38,38] fp32
               const unsigned short* __restrict__ wb,  // [256,512] bf16
               const float* __restrict__ cb,           // [255] fp32
               float* __restrict__ out)                // [46208,255] fp32
{
    __shared__ unsigned smem[2 * CH_DW];               // 33,792 B
    unsigned short* As0 = (unsigned short*)smem;
    unsigned short* As1 = (unsigned short*)(smem + CH_DW);

    const int t    = threadIdx.x;
    const int w    = t >> 6;       // wave id -> n-slice w*64
    const int lane = t & 63;
    const int l15  = lane & 15;
    const int q    = lane >> 4;

    // bijective chunked XCD swizzle: nwg = 722 = 8*90 + 2.
    const int orig = blockIdx.x;
    const int xcd  = orig & 7;
    const int rank = orig >> 3;
    const int wgid = (xcd < 2 ? xcd * 91 : 182 + (xcd - 2) * 90) + rank;
    const int m0   = wgid * BM;

    // staging coords: thread owns 4m x 4k micro-tiles; 2 slabs of 64 k/chunk
    const int mq4 = (t & 15) * 4;          // m-quad base within block (0..60)
    const int kq4 = (t >> 4) * 4;          // k-quad base within 64-k slab (0..60)
    const int m4  = m0 + mq4;
    const int bi  = m4 / BHW;              // never straddles b (BHW%4==0, m4%4==0)
    const int hw  = m4 - bi * BHW;
    const float* pb0 = xin + (size_t)bi * (CIN_K * BHW) + hw;

    alignas(16) float P[2][4][4];          // prefetch set: [slab][kk][m], 32 VGPRs

    auto LOADREG = [&](int c) {            // issue 8 independent float4 loads
#pragma unroll
        for (int s = 0; s < 2; ++s)
#pragma unroll
            for (int kk = 0; kk < 4; ++kk)
                *(float4*)&P[s][kk][0] =
                    *(const float4*)(pb0 + (size_t)(c * KCH + s * 64 + kq4 + kk) * BHW);
    };
    auto PACKWRITE = [&](unsigned short* dst) {   // 4x4 reg transpose -> LDS
#pragma unroll
        for (int s = 0; s < 2; ++s)
#pragma unroll
            for (int r = 0; r < 4; ++r) {
                unsigned lo = pk2bf(P[s][0][r], P[s][1][r]);
                unsigned hi = pk2bf(P[s][2][r], P[s][3][r]);
                *(uint2*)(&dst[(mq4 + r) * ROWE + s * 64 + kq4]) = make_uint2(lo, hi);
            }
    };

    floatx4 acc[4][4];
#pragma unroll
    for (int i = 0; i < 4; ++i)
#pragma unroll
        for (int j = 0; j < 4; ++j)
            acc[i][j] = (floatx4){0.f, 0.f, 0.f, 0.f};

    // B frag addr: n = w*64 + j*16 + l15, k = c*128 + kc*32 + q*8
    const unsigned short* pbw = wb + (size_t)(w * 64 + l15) * CIN_K + q * 8;

    auto COMPUTE = [&](const unsigned short* src, int c) {
#pragma unroll
        for (int kc = 0; kc < 4; ++kc) {
            bf16x8 bfr[4], af[4];
#pragma unroll
            for (int j = 0; j < 4; ++j) {
                uint4 bv = *(const uint4*)(pbw + (size_t)j * 16 * CIN_K
                                           + c * KCH + kc * 32);
                bfr[j] = __builtin_bit_cast(bf16x8, bv);
            }
#pragma unroll
            for (int i = 0; i < 4; ++i) {
                int4 av = *(const int4*)(&src[(i * 16 + l15) * ROWE + kc * 32 + q * 8]);
                af[i] = __builtin_bit_cast(bf16x8, av);
            }
#pragma unroll
            for (int i = 0; i < 4; ++i)
#pragma unroll
                for (int j = 0; j < 4; ++j)
                    acc[i][j] = __builtin_amdgcn_mfma_f32_16x16x32_bf16(
                                    af[i], bfr[j], acc[i][j], 0, 0, 0);
        }
    };

    // -------- pipeline ------------------------------------------------------
    LOADREG(0);
    PACKWRITE(As0);
    LOADREG(1);                    // prologue: drained at the barrier (one-time)
    __syncthreads();               // As0 published

#pragma unroll
    for (int c = 0; c < 4; ++c) {
        const unsigned short* cur = (c & 1) ? As1 : As0;
        unsigned short*       nxt = (c & 1) ? As0 : As1;
        COMPUTE(cur, c);
        if (c < 3) {
            __syncthreads();       // readers of nxt (iter c-1) done; P arrived
            PACKWRITE(nxt);
            __syncthreads();       // nxt published
            if (c < 2) LOADREG(c + 2);   // post-barrier issue -> flies under
                                         // COMPUTE(c+1), drained at its end
        }
    }

    // -------- fused YOLO decode (in place on acc) --------------------------
    // C/D layout: col(n) = l15 (+16j), row(m) = i*16 + q*4 + r
#pragma unroll
    for (int j = 0; j < 4; ++j) {
        int   n    = w * 64 + j * 16 + l15;
        int   nc   = n < NOUT ? n : NOUT - 1;
        int   ai   = nc / 85;
        int   ji   = nc - ai * 85;
        float bias = cb[nc];
        float aw   = (ai == 0) ? 30.f : (ai == 1) ? 62.f : 59.f;
        float ah   = (ai == 0) ? 61.f : (ai == 1) ? 45.f : 119.f;
#pragma unroll
        for (int i = 0; i < 4; ++i)
#pragma unroll
            for (int r = 0; r < 4; ++r) {
                int   md  = m0 + i * 16 + q * 4 + r;
                int   rem = md % BHW;
                int   hh  = rem / WW_;
                float v   = acc[i][j][r] + bias;
                float res;
                if (ji == 0)      res = (1.f / (1.f + __expf(-v)) + (float)(rem - hh * WW_)) * 16.f;
                else if (ji == 1) res = (1.f / (1.f + __expf(-v)) + (float)hh) * 16.f;
                else if (ji == 2) res = __expf(v) * aw;
                else if (ji == 3) res = __expf(v) * ah;
                else              res = v;
                acc[i][j][r] = res;
            }
    }

    // -------- epilogue: LDS transpose + aligned stores, 2 passes of 32 rows -
    float* EP = (float*)smem;
#pragma unroll
    for (int p = 0; p < 2; ++p) {
        __syncthreads();                   // previous LDS readers done
#pragma unroll
        for (int i2 = 0; i2 < 2; ++i2) {
            const int i = p * 2 + i2;
#pragma unroll
            for (int j = 0; j < 4; ++j)
#pragma unroll
                for (int r = 0; r < 4; ++r)
                    EP[(i2 * 16 + q * 4 + r) * EP_DW + w * 64 + j * 16 + l15] =
                        acc[i][j][r];
        }
        __syncthreads();

        // wave w stores rows [p*32 + w*8, +8): 8*255 = 2040 floats, 16B-aligned
        const float* EPb = (const float*)smem + (w * 8) * EP_DW;
        float*       ob  = out + (size_t)(m0 + p * 32 + w * 8) * NOUT;
#pragma unroll
        for (int s2 = 0; s2 < 8; ++s2) {
            int f4 = s2 * 64 + lane;       // float4 index, 0..509
            if (f4 < 510) {
                int   f = f4 * 4;
                float vs[4];
#pragma unroll
                for (int e = 0; e < 4; ++e) {
                    int fe = f + e;
                    int mr = fe / NOUT;
                    int x  = fe - mr * NOUT;
                    vs[e]  = EPb[mr * EP_DW + x];
                }
                *(float4*)(ob + f) = make_float4(vs[0], vs[1], vs[2], vs[3]);
            }
        }
    }
}

extern "C" void kernel_launch(void* const* d_in, const int* in_sizes, int n_in,
                              void* d_out, int out_size, void* d_ws, size_t ws_size,
                              hipStream_t stream) {
    const float* xin = (const float*)d_in[0];
    const float* cw  = (const float*)d_in[1];
    const float* cb  = (const float*)d_in[2];
    float*       out = (float*)d_out;
    unsigned short* wb = (unsigned short*)d_ws;   // 256*512*2 = 256 KiB

    hipLaunchKernelGGL(conv_w_to_bf16, dim3(64), dim3(256), 0, stream, cw, wb);
    hipLaunchKernelGGL(yolo_head, dim3(MTOT / BM), dim3(256), 0, stream,
                       xin, wb, cb, out);
}